// Round 4
// baseline (234.128 us; speedup 1.0000x reference)
//
#include <hip/hip_runtime.h>
#include <math.h>

namespace {

constexpr int kRays    = 65536;
constexpr int kSamples = 128;
constexpr float kEpsilonBig = 1.0e10f;   // EPSILON in the reference

// d_out layout: outputs concatenated flat in reference return order
constexpr int OFF_RGB   = 0;                          // (kRays, 3)
constexpr int OFF_DEPTH = OFF_RGB + kRays * 3;        // (kRays,)
constexpr int OFF_W     = OFF_DEPTH + kRays;          // (kRays, 128)
constexpr int OFF_M     = OFF_W + kRays * kSamples;   // (kRays, 128)
constexpr int OFF_ACC   = OFF_M + kRays * kSamples;   // (kRays,)
constexpr int OFF_DISP  = OFF_ACC + kRays;            // (kRays,)

__global__ __launch_bounds__(256) void volume_render_kernel(
    const float* __restrict__ rf,     // (kRays, 128, 4)
    const float* __restrict__ depth,  // (kRays, 128)
    const float* __restrict__ rd,     // (kRays, 3)
    float* __restrict__ out)
{
  const int lane = threadIdx.x & 63;
  const int ray  = (blockIdx.x * blockDim.x + threadIdx.x) >> 6;  // wave id

  // ---- coalesced loads: lane owns samples s0=lane and s1=lane+64 ----
  const float4* rf4 = reinterpret_cast<const float4*>(rf);
  const float4 v0 = rf4[ray * kSamples + lane];
  const float4 v1 = rf4[ray * kSamples + lane + 64];
  const float  d0 = depth[ray * kSamples + lane];
  const float  d1 = depth[ray * kSamples + lane + 64];

  // ray index is wave-uniform: force scalar loads for ray_directions
  const int uray = __builtin_amdgcn_readfirstlane(ray);
  const float rx = rd[uray * 3 + 0];
  const float ry = rd[uray * 3 + 1];
  const float rz = rd[uray * 3 + 2];
  const float nrm = sqrtf(rx * rx + ry * ry + rz * rz);

  // ---- deltas (need depth[s+1]) ----
  float nd0 = __shfl_down(d0, 1);          // depth[lane+1] for lane<63
  const float d_at_64 = __shfl(d1, 0);     // depth[64]
  if (lane == 63) nd0 = d_at_64;
  const float nd1 = __shfl_down(d1, 1);    // depth[lane+65]

  const float delta0 = (nd0 - d0) * nrm;
  const float delta1 = (lane == 63) ? kEpsilonBig * nrm : (nd1 - d1) * nrm;

  // ---- alpha (f32, matches np f32 exp to ~1 ulp) ----
  const float sig0 = fmaxf(v0.w, 0.0f);
  const float sig1 = fmaxf(v1.w, 0.0f);
  const float alpha0 = 1.0f - expf(-sig0 * delta0);
  const float alpha1 = 1.0f - expf(-sig1 * delta1);

  // t_i rounded to f32 exactly like the reference, then promoted:
  // the f64 scan multiplies the SAME f32 factors the reference does,
  // eliminating tree-reassociation error in T_i (protects the mask threshold)
  const double t0 = (double)((1.0f - alpha0) + 1e-10f);
  const double t1 = (double)((1.0f - alpha1) + 1e-10f);

  // ---- exclusive cumprod over 128 samples (two 64-wide wave scans, f64) ----
  double p0 = t0, p1 = t1;
#pragma unroll
  for (int off = 1; off < 64; off <<= 1) {
    const double u0 = __shfl_up(p0, off);
    const double u1 = __shfl_up(p1, off);
    if (lane >= off) { p0 *= u0; p1 *= u1; }
  }
  const double tot0 = __shfl(p0, 63);      // prod t[0..63]
  double e0 = __shfl_up(p0, 1);            // inclusive -> exclusive
  double e1 = __shfl_up(p1, 1);
  if (lane == 0) { e0 = 1.0; e1 = 1.0; }
  const double T0 = e0;                    // T_i at s = lane
  const double T1 = tot0 * e1;             // T_i at s = lane + 64

  const float w0 = (float)(T0 * (double)alpha0);
  const float w1 = (float)(T1 * (double)alpha1);

  // numpy compares f32 T_i against f32-cast 0.001
  const double thr = (double)0.001f;

  // ---- full-size outputs (coalesced) ----
  const int base = ray * kSamples + lane;
  out[OFF_W + base]      = w0;
  out[OFF_W + base + 64] = w1;
  out[OFF_M + base]      = (T0 > thr) ? 1.0f : 0.0f;
  out[OFF_M + base + 64] = (T1 > thr) ? 1.0f : 0.0f;

  // ---- wave reductions: rgb (3), acc, depth (f32 butterflies) ----
  float r   = w0 * v0.x + w1 * v1.x;
  float g   = w0 * v0.y + w1 * v1.y;
  float b   = w0 * v0.z + w1 * v1.z;
  float acc = w0 + w1;
  float dm  = w0 * d0 + w1 * d1;
#pragma unroll
  for (int off = 32; off > 0; off >>= 1) {
    r   += __shfl_xor(r, off);
    g   += __shfl_xor(g, off);
    b   += __shfl_xor(b, off);
    acc += __shfl_xor(acc, off);
    dm  += __shfl_xor(dm, off);
  }

  if (lane == 0) {
    out[OFF_RGB + ray * 3 + 0] = r;
    out[OFF_RGB + ray * 3 + 1] = g;
    out[OFF_RGB + ray * 3 + 2] = b;
    out[OFF_DEPTH + ray] = dm;
    out[OFF_ACC + ray]   = acc;
    const float q = dm / acc;             // may be NaN (0/0)
    float disp;
    if (isnan(q)) {
      disp = 0.0f;                        // jnp.maximum propagates NaN -> where() zeroes it
    } else {
      disp = 1.0f / fmaxf(1e-10f, q);     // matches reference
    }
    out[OFF_DISP + ray] = disp;
  }
}

}  // namespace

extern "C" void kernel_launch(void* const* d_in, const int* in_sizes, int n_in,
                              void* d_out, int out_size, void* d_ws, size_t ws_size,
                              hipStream_t stream) {
  const float* rf    = (const float*)d_in[0];   // radiance_field (65536,128,4)
  const float* depth = (const float*)d_in[1];   // depth_values   (65536,128)
  const float* rd    = (const float*)d_in[2];   // ray_directions (65536,3)
  float* out = (float*)d_out;

  // one wave per ray: 65536 waves = 16384 blocks of 256 threads (4 waves)
  const int blocks = kRays / 4;
  volume_render_kernel<<<blocks, 256, 0, stream>>>(rf, depth, rd, out);
}

// Round 5
// 231.324 us; speedup vs baseline: 1.0121x; 1.0121x over previous
//
#include <hip/hip_runtime.h>
#include <math.h>

namespace {

constexpr int kRays    = 65536;
constexpr int kSamples = 128;
constexpr float kEpsilonBig = 1.0e10f;   // EPSILON in the reference

// d_out layout: outputs concatenated flat in reference return order
constexpr int OFF_RGB   = 0;                          // (kRays, 3)
constexpr int OFF_DEPTH = OFF_RGB + kRays * 3;        // (kRays,)
constexpr int OFF_W     = OFF_DEPTH + kRays;          // (kRays, 128)
constexpr int OFF_M     = OFF_W + kRays * kSamples;   // (kRays, 128)
constexpr int OFF_ACC   = OFF_M + kRays * kSamples;   // (kRays,)
constexpr int OFF_DISP  = OFF_ACC + kRays;            // (kRays,)

// ---- DPP cross-lane primitives (VALU pipe — no ds_bpermute, no lgkmcnt) ----
// f32 sum step: invalid/masked lanes contribute 0 (additive identity).
#define DPP_ADD_F32(v, ctrl, rmask)                                         \
  (v) += __int_as_float(__builtin_amdgcn_update_dpp(                        \
      0, __float_as_int(v), (ctrl), (rmask), 0xf, true))

// full 64-lane inclusive sum scan; lane 63 ends with the wave total
#define DPP_REDUCE_F32(v)                                                   \
  do {                                                                      \
    DPP_ADD_F32(v, 0x111, 0xf); /* row_shr:1  */                            \
    DPP_ADD_F32(v, 0x112, 0xf); /* row_shr:2  */                            \
    DPP_ADD_F32(v, 0x114, 0xf); /* row_shr:4  */                            \
    DPP_ADD_F32(v, 0x118, 0xf); /* row_shr:8  */                            \
    DPP_ADD_F32(v, 0x142, 0xa); /* row_bcast:15 -> rows 1,3 */              \
    DPP_ADD_F32(v, 0x143, 0xc); /* row_bcast:31 -> rows 2,3 */              \
  } while (0)

// f64 product step: invalid/masked lanes keep old = 1.0 (multiplicative identity)
#define DPP_MUL_F64(p, ctrl, rmask)                                         \
  do {                                                                      \
    unsigned long long _b = (unsigned long long)__double_as_longlong(p);    \
    int _lo = __builtin_amdgcn_update_dpp(                                  \
        0x00000000, (int)(unsigned)(_b & 0xffffffffull), (ctrl), (rmask),   \
        0xf, false);                                                        \
    int _hi = __builtin_amdgcn_update_dpp(                                  \
        0x3ff00000, (int)(unsigned)(_b >> 32), (ctrl), (rmask),             \
        0xf, false);                                                        \
    (p) *= __longlong_as_double(                                            \
        (long long)(((unsigned long long)(unsigned)_hi << 32) |             \
                    (unsigned)_lo));                                        \
  } while (0)

__global__ __launch_bounds__(256) void volume_render_kernel(
    const float* __restrict__ rf,     // (kRays, 128, 4)
    const float* __restrict__ depth,  // (kRays, 128)
    const float* __restrict__ rd,     // (kRays, 3)
    float* __restrict__ out)
{
  const int lane = threadIdx.x & 63;
  const int ray  = (blockIdx.x * blockDim.x + threadIdx.x) >> 6;  // wave id

  // ---- pair-blocked layout: lane i owns contiguous samples 2i, 2i+1 ----
  const float4* rf4 = reinterpret_cast<const float4*>(rf);
  const int rbase = ray * kSamples + 2 * lane;
  const float4 v0 = rf4[rbase];        // sample 2i
  const float4 v1 = rf4[rbase + 1];    // sample 2i+1
  const float2 dd = reinterpret_cast<const float2*>(depth)[ray * 64 + lane];

  // ray index is wave-uniform: scalar loads for ray_directions
  const int uray = __builtin_amdgcn_readfirstlane(ray);
  const float rx = rd[uray * 3 + 0];
  const float ry = rd[uray * 3 + 1];
  const float rz = rd[uray * 3 + 2];
  const float nrm = sqrtf(rx * rx + ry * ry + rz * rz);

  // ---- deltas: even-sample delta is lane-local; odd needs 1 neighbor shfl ----
  const float dnext = __shfl_down(dd.x, 1);          // depth[2i+2]
  const float delta0 = (dd.y - dd.x) * nrm;
  const float delta1 = (lane == 63) ? kEpsilonBig * nrm : (dnext - dd.y) * nrm;

  // ---- alpha (f32, ~1 ulp vs np's f32 exp) ----
  const float alpha0 = 1.0f - expf(-fmaxf(v0.w, 0.0f) * delta0);
  const float alpha1 = 1.0f - expf(-fmaxf(v1.w, 0.0f) * delta1);

  // t_i rounded to f32 exactly like the reference, then promoted; the f64
  // scan multiplies the SAME f32 factors the reference multiplies
  const float t0f = (1.0f - alpha0) + 1e-10f;
  const float t1f = (1.0f - alpha1) + 1e-10f;

  // ---- exclusive cumprod: local pair product + 64-lane DPP scan (f64) ----
  double P = (double)t0f * (double)t1f;              // lane product c_i
  DPP_MUL_F64(P, 0x111, 0xf);  // row_shr:1
  DPP_MUL_F64(P, 0x112, 0xf);  // row_shr:2
  DPP_MUL_F64(P, 0x114, 0xf);  // row_shr:4
  DPP_MUL_F64(P, 0x118, 0xf);  // row_shr:8
  DPP_MUL_F64(P, 0x142, 0xa);  // row_bcast:15 -> rows 1,3
  DPP_MUL_F64(P, 0x143, 0xc);  // row_bcast:31 -> rows 2,3
  // P = inclusive prefix product of c over lanes

  double e = __shfl_up(P, 1);                        // exclusive shift
  if (lane == 0) e = 1.0;
  const double T0 = e;                               // T at sample 2i
  const double T1 = e * (double)t0f;                 // T at sample 2i+1

  const float w0 = (float)(T0 * (double)alpha0);
  const float w1 = (float)(T1 * (double)alpha1);

  // numpy compares f32 T_i against f32-cast 0.001
  const double thr = (double)0.001f;

  // ---- full-size outputs (float2, coalesced) ----
  reinterpret_cast<float2*>(out + OFF_W)[ray * 64 + lane] =
      make_float2(w0, w1);
  reinterpret_cast<float2*>(out + OFF_M)[ray * 64 + lane] =
      make_float2((T0 > thr) ? 1.0f : 0.0f, (T1 > thr) ? 1.0f : 0.0f);

  // ---- wave reductions via DPP (result in lane 63) ----
  float r   = w0 * v0.x + w1 * v1.x;
  float g   = w0 * v0.y + w1 * v1.y;
  float b   = w0 * v0.z + w1 * v1.z;
  float acc = w0 + w1;
  float dm  = w0 * dd.x + w1 * dd.y;
  DPP_REDUCE_F32(r);
  DPP_REDUCE_F32(g);
  DPP_REDUCE_F32(b);
  DPP_REDUCE_F32(acc);
  DPP_REDUCE_F32(dm);

  if (lane == 63) {
    out[OFF_RGB + ray * 3 + 0] = r;
    out[OFF_RGB + ray * 3 + 1] = g;
    out[OFF_RGB + ray * 3 + 2] = b;
    out[OFF_DEPTH + ray] = dm;
    out[OFF_ACC + ray]   = acc;
    const float q = dm / acc;             // may be NaN (0/0)
    float disp;
    if (isnan(q)) {
      disp = 0.0f;                        // jnp.maximum propagates NaN -> where() zeroes it
    } else {
      disp = 1.0f / fmaxf(1e-10f, q);     // matches reference
    }
    out[OFF_DISP + ray] = disp;
  }
}

}  // namespace

extern "C" void kernel_launch(void* const* d_in, const int* in_sizes, int n_in,
                              void* d_out, int out_size, void* d_ws, size_t ws_size,
                              hipStream_t stream) {
  const float* rf    = (const float*)d_in[0];   // radiance_field (65536,128,4)
  const float* depth = (const float*)d_in[1];   // depth_values   (65536,128)
  const float* rd    = (const float*)d_in[2];   // ray_directions (65536,3)
  float* out = (float*)d_out;

  // one wave per ray: 65536 waves = 16384 blocks of 256 threads (4 waves)
  const int blocks = kRays / 4;
  volume_render_kernel<<<blocks, 256, 0, stream>>>(rf, depth, rd, out);
}